// Round 7
// baseline (127.809 us; speedup 1.0000x reference)
//
#include <hip/hip_runtime.h>
#include <hip/hip_bf16.h>
#include <math.h>

// VectorQuantizer: z [65536 x 64] fp32, codebook [1024 x 64] fp32.
// dist = (||z||^2 - 2 z.e) + ||e||^2, argmin_k, first-occurrence ties.
// Numerics identical to R4/R5/R6 (all passed, absmax 0): exact np pairwise
// sumsq for S/cn; d via f16 split-2 3-pass MFMA (err ~1e-8 << absorption bin
// 7.6e-6); dist = (S - 2d) + cn explicit __f*_rn; u64-key lexicographic merge.
//
// R6 post-mortem: latency-bound on B-frag global loads (~100k stall cyc/SIMD,
// VALUBusy 23%) — L2/L3 latency exposed at <2 waves/SIMD. R7: B-frag tiles
// stream through DOUBLE-BUFFERED LDS via global_load_lds width=16 (async DMA
// issued one tile ahead; one barrier/tile), and occupancy restored: 256-thr
// blocks, 4 waves x 32 rows, K-split 2 -> grid 1024 = 4 blocks/CU = 16
// waves/CU. Projected wall: DS pipe ~11.5us/CU; VALU/MFMA overlap beneath.

#define D      64
#define K      1024
#define BLOCK  256

typedef _Float16 half8_t __attribute__((ext_vector_type(8)));
typedef float    floatx4 __attribute__((ext_vector_type(4)));
typedef unsigned long long u64;

// ws layout
#define WS_KEYS_OFF  0            // u64[65536]          (512 KB)
#define WS_CN_OFF    524288       // float[1024]         (4 KB)
#define WS_EF_OFF    528384       // _Float16[131072]    (256 KB)
// per 64-code tile t (16 KB): frag (spl,ch,ct) at half-offset
//   t*8192 + 512*((spl*2+ch)*4+ct) + 8*lane

__device__ __forceinline__ void gld_lds16(const void* g, void* l) {
    __builtin_amdgcn_global_load_lds(
        (const __attribute__((address_space(1))) void*)g,
        (__attribute__((address_space(3))) void*)l, 16, 0, 0);
}

// numpy pairwise sumsq (n=64): 8 stride-8 accs of fl(x^2), tree combine.
__device__ __forceinline__ float np_sumsq64_p(const float* __restrict__ x) {
    float r[8];
    {
        float4 v0 = *(const float4*)(x);
        float4 v1 = *(const float4*)(x + 4);
        r[0] = __fmul_rn(v0.x, v0.x); r[1] = __fmul_rn(v0.y, v0.y);
        r[2] = __fmul_rn(v0.z, v0.z); r[3] = __fmul_rn(v0.w, v0.w);
        r[4] = __fmul_rn(v1.x, v1.x); r[5] = __fmul_rn(v1.y, v1.y);
        r[6] = __fmul_rn(v1.z, v1.z); r[7] = __fmul_rn(v1.w, v1.w);
    }
#pragma unroll
    for (int i = 8; i < 64; i += 8) {
        float4 v0 = *(const float4*)(x + i);
        float4 v1 = *(const float4*)(x + i + 4);
        r[0] = __fadd_rn(r[0], __fmul_rn(v0.x, v0.x));
        r[1] = __fadd_rn(r[1], __fmul_rn(v0.y, v0.y));
        r[2] = __fadd_rn(r[2], __fmul_rn(v0.z, v0.z));
        r[3] = __fadd_rn(r[3], __fmul_rn(v0.w, v0.w));
        r[4] = __fadd_rn(r[4], __fmul_rn(v1.x, v1.x));
        r[5] = __fadd_rn(r[5], __fmul_rn(v1.y, v1.y));
        r[6] = __fadd_rn(r[6], __fmul_rn(v1.z, v1.z));
        r[7] = __fadd_rn(r[7], __fmul_rn(v1.w, v1.w));
    }
    return __fadd_rn(__fadd_rn(__fadd_rn(r[0], r[1]), __fadd_rn(r[2], r[3])),
                     __fadd_rn(__fadd_rn(r[4], r[5]), __fadd_rn(r[6], r[7])));
}

// ---- precompute: code norms + f16 split-2 B-frags in MFMA lane order ----
__global__ void vq_pre(const float* __restrict__ cb, float* __restrict__ cn,
                       _Float16* __restrict__ ef) {
    const int k = blockIdx.x * 64 + threadIdx.x;
    if (k >= K) return;
    cn[k] = np_sumsq64_p(cb + (long)k * D);
    const int t = k >> 6, ct = (k >> 4) & 3, l16 = k & 15;
#pragma unroll
    for (int ch = 0; ch < 2; ++ch)
#pragma unroll
        for (int quad = 0; quad < 4; ++quad) {
            const float* p = cb + (long)k * D + ch * 32 + quad * 8;
            half8_t h1, h2;
#pragma unroll
            for (int j = 0; j < 8; ++j) {
                float x10 = __fmul_rn(p[j], 1024.0f);        // exact pow2 scale
                _Float16 g1 = (_Float16)x10;
                h1[j] = g1;
                h2[j] = (_Float16)(__fmul_rn(__fsub_rn(x10, (float)g1), 2048.0f));
            }
            const int base = t * 8192 + 128 * quad + 8 * l16;
            *(half8_t*)(ef + base + 512 * (ch * 4 + ct))       = h1;
            *(half8_t*)(ef + base + 512 * ((2 + ch) * 4 + ct)) = h2;
        }
}

// ---- main: 128 rows x 512 codes per 4-wave block; LDS-dbuf B stream ----
__global__ __launch_bounds__(BLOCK, 4) void vq_main(
    const float* __restrict__ z, const _Float16* __restrict__ ef,
    const float* __restrict__ cn, u64* __restrict__ keys) {
    // zf (128 x 68 f32 = 34816 B) unioned with the two 16 KB frag buffers
    __shared__ __align__(16) char smem[34816];
    __shared__ float sS[128];
    __shared__ float sCn[512];
    float*    zf   = (float*)smem;
    _Float16* bufs = (_Float16*)smem;     // buf b at bufs + b*8192

    const int tid  = threadIdx.x;
    const int lane = tid & 63;
    const int wv   = tid >> 6;
    const int quad = lane >> 4;
    const int l16  = lane & 15;
    const int rb = blockIdx.x >> 1, ks = blockIdx.x & 1;
    const long rowbase = (long)rb * 128;
    const int kb0 = ks * 512;

    // ---- stage z (coalesced) + this slice's code norms ----
    const float4* gz = (const float4*)(z + rowbase * D);
#pragma unroll
    for (int i = 0; i < 8; ++i) {
        int idx4 = i * BLOCK + tid;
        int r = idx4 >> 4, j = idx4 & 15;
        *(float4*)(zf + r * 68 + j * 4) = gz[idx4];
    }
    sCn[tid]       = cn[kb0 + tid];
    sCn[tid + 256] = cn[kb0 + tid + 256];
    __syncthreads();

    // row norms (exact np chain)
    if (tid < 128) sS[tid] = np_sumsq64_p(zf + tid * 68);

    // A-frags: register-resident f16 splits; wave wv -> rows wv*32 .. +31
    half8_t a1[2][2], a2[2][2];
#pragma unroll
    for (int rt = 0; rt < 2; ++rt) {
        const int row = wv * 32 + rt * 16 + l16;
#pragma unroll
        for (int ch = 0; ch < 2; ++ch) {
            const float* p = zf + row * 68 + ch * 32 + quad * 8;
            float4 f0 = *(const float4*)(p);
            float4 f1 = *(const float4*)(p + 4);
            float xs[8] = {f0.x, f0.y, f0.z, f0.w, f1.x, f1.y, f1.z, f1.w};
#pragma unroll
            for (int j = 0; j < 8; ++j) {
                _Float16 h1 = (_Float16)xs[j];
                a1[rt][ch][j] = h1;
                a2[rt][ch][j] =
                    (_Float16)(__fmul_rn(__fsub_rn(xs[j], (float)h1), 2048.0f));
            }
        }
    }
    __syncthreads();   // all zf reads done (sS + frags); sS visible

    float myS[2][4];
#pragma unroll
    for (int rt = 0; rt < 2; ++rt)
#pragma unroll
        for (int r = 0; r < 4; ++r)
            myS[rt][r] = sS[wv * 32 + rt * 16 + quad * 4 + r];

    float bv[2][4];
    int   bi[2][4];
#pragma unroll
    for (int rt = 0; rt < 2; ++rt)
#pragma unroll
        for (int r = 0; r < 4; ++r) { bv[rt][r] = INFINITY; bi[rt][r] = 0; }

    const char* eb = (const char*)(ef + (long)ks * 8 * 8192);

    // stage tile 0 (async DMA: wave wv copies its 4 KB quarter)
    {
        const char* g = eb + wv * 4096 + lane * 16;
        char* l = (char*)bufs + wv * 4096;       // wave-uniform dest base
#pragma unroll
        for (int i = 0; i < 4; ++i) gld_lds16(g + i * 1024, l + i * 1024);
    }
    __syncthreads();   // tile 0 staged (barrier drains vmcnt)

    for (int t = 0; t < 8; ++t) {
        const _Float16* cur = bufs + (t & 1) * 8192;
        // prefetch tile t+1 into the other buffer (async, lands by barrier)
        if (t < 7) {
            const char* g = eb + (t + 1) * 16384 + wv * 4096 + lane * 16;
            char* l = (char*)bufs + ((t + 1) & 1) * 8192 * 2 + wv * 4096;
#pragma unroll
            for (int i = 0; i < 4; ++i) gld_lds16(g + i * 1024, l + i * 1024);
        }

        const _Float16* tb = cur + 8 * lane;
        const int kbase = kb0 + t * 64;
#pragma unroll
        for (int ct = 0; ct < 4; ++ct) {
            half8_t b1[2], b2[2];
#pragma unroll
            for (int ch = 0; ch < 2; ++ch) {
                b1[ch] = *(const half8_t*)(tb + 512 * (ch * 4 + ct));
                b2[ch] = *(const half8_t*)(tb + 512 * ((2 + ch) * 4 + ct));
            }
            const float cnv = sCn[t * 64 + ct * 16 + l16];
            const int kg = kbase + ct * 16 + l16;
#pragma unroll
            for (int rt = 0; rt < 2; ++rt) {
                floatx4 aM = (floatx4){0.f, 0.f, 0.f, 0.f};
                floatx4 aC = (floatx4){0.f, 0.f, 0.f, 0.f};
                aM = __builtin_amdgcn_mfma_f32_16x16x32_f16(a1[rt][0], b1[0], aM, 0, 0, 0);
                aM = __builtin_amdgcn_mfma_f32_16x16x32_f16(a1[rt][1], b1[1], aM, 0, 0, 0);
                aC = __builtin_amdgcn_mfma_f32_16x16x32_f16(a1[rt][0], b2[0], aC, 0, 0, 0);
                aC = __builtin_amdgcn_mfma_f32_16x16x32_f16(a1[rt][1], b2[1], aC, 0, 0, 0);
                aC = __builtin_amdgcn_mfma_f32_16x16x32_f16(a2[rt][0], b1[0], aC, 0, 0, 0);
                aC = __builtin_amdgcn_mfma_f32_16x16x32_f16(a2[rt][1], b1[1], aC, 0, 0, 0);
                // C layout: col=l16 (code), row=quad*4+r
#pragma unroll
                for (int r = 0; r < 4; ++r) {
                    float ds = fmaf(aC[r], 0x1p-11f, aM[r]);   // 1024*d
                    float t2 = __fmul_rn(ds, 0x1p-9f);         // 2d, exact pow2
                    float dist = __fadd_rn(__fsub_rn(myS[rt][r], t2), cnv);
                    if (dist < bv[rt][r]) { bv[rt][r] = dist; bi[rt][r] = kg; }
                }
            }
        }
        __syncthreads();  // t+1 staged; cur reads done before t+2 overwrites
    }

    // reduce over the 16 code-columns, then merge k-slices via u64 atomicMin
#pragma unroll
    for (int rt = 0; rt < 2; ++rt)
#pragma unroll
        for (int r = 0; r < 4; ++r) {
            float v = bv[rt][r];
            int   x = bi[rt][r];
#pragma unroll
            for (int off = 1; off <= 8; off <<= 1) {
                float ov = __shfl_xor(v, off);
                int   ox = __shfl_xor(x, off);
                if (ov < v || (ov == v && ox < x)) { v = ov; x = ox; }
            }
            if (l16 == 0) {
                const long row = rowbase + wv * 32 + rt * 16 + quad * 4 + r;
                u64 key = ((u64)__float_as_uint(v) << 32) | (unsigned)x;
                atomicMin(&keys[row], key);
            }
        }
}

// ---- resolve: unpack keys, write idx + gather z_q ----
__global__ void vq_resolve(const float* __restrict__ cb,
                           const u64* __restrict__ keys,
                           float* __restrict__ zq, float* __restrict__ idx_out) {
    const int gid = blockIdx.x * 256 + threadIdx.x;
    const int row = gid >> 4, j = gid & 15;
    const unsigned k = (unsigned)(keys[row] & 0xFFFFFFFFu);
    ((float4*)zq)[gid] = ((const float4*)cb)[(long)k * 16 + j];
    if (j == 0) idx_out[row] = (float)k;
}

extern "C" void kernel_launch(void* const* d_in, const int* in_sizes, int n_in,
                              void* d_out, int out_size, void* d_ws, size_t ws_size,
                              hipStream_t stream) {
    const float* z  = (const float*)d_in[0];
    const float* cb = (const float*)d_in[1];

    const int n_rows = in_sizes[0] / D;                 // 65536
    float* zq      = (float*)d_out;
    float* idx_out = zq + (long)n_rows * D;

    u64*      ws_keys = (u64*)((char*)d_ws + WS_KEYS_OFF);
    float*    ws_cn   = (float*)((char*)d_ws + WS_CN_OFF);
    _Float16* ws_ef   = (_Float16*)((char*)d_ws + WS_EF_OFF);

    hipMemsetAsync(ws_keys, 0xFF, (size_t)n_rows * sizeof(u64), stream);
    vq_pre<<<K / 64, 64, 0, stream>>>(cb, ws_cn, ws_ef);
    vq_main<<<(n_rows / 128) * 2, BLOCK, 0, stream>>>(z, ws_ef, ws_cn, ws_keys);
    vq_resolve<<<(n_rows * 16) / 256, 256, 0, stream>>>(cb, ws_keys, zq, idx_out);
}

// Round 8
// 101.085 us; speedup vs baseline: 1.2644x; 1.2644x over previous
//
#include <hip/hip_runtime.h>
#include <hip/hip_bf16.h>
#include <math.h>

// VectorQuantizer: z [65536 x 64] fp32, codebook [1024 x 64] fp32.
// dist = (||z||^2 - 2 z.e) + ||e||^2, argmin_k, first-occurrence ties.
// Numerics identical to R4-R7 (all passed, absmax 0): exact np pairwise
// sumsq for S/cn; d via f16 split-2 3-pass MFMA (err ~1e-8 << absorption
// bin 7.6e-6); dist = (S - 2d) + cn explicit __f*_rn; (val, lowest-k) reduce.
//
// R7 post-mortem: __launch_bounds__(256,4) forced 64 VGPRs -> scratch spill
// (WRITE 49MB vs 17MB outputs); plus ~55us of memset/pre/resolve dispatches
// and inter-kernel gaps. R8: (1) launch_bounds(256,2) -> ~110 live regs fit,
// no spill; (2) NO K-split: each block scans all 16 dbuf'd frag tiles
// (global_load_lds w=16 prefetch, one barrier/tile) and writes idx + zq
// directly -> memset + atomics + resolve kernels deleted (2 dispatches
// + 2 gaps). Projected main wall: DS pipe ~12us/CU; VALU/MFMA beneath.

#define D      64
#define K      1024
#define BLOCK  256

typedef _Float16 half8_t __attribute__((ext_vector_type(8)));
typedef float    floatx4 __attribute__((ext_vector_type(4)));

// ws layout
#define WS_CN_OFF    0            // float[1024]         (4 KB)
#define WS_EF_OFF    4096         // _Float16[131072]    (256 KB)
// per 64-code tile t (16 KB): frag (spl,ch,ct) at half-offset
//   t*8192 + 512*((spl*2+ch)*4+ct) + 8*lane

__device__ __forceinline__ void gld_lds16(const void* g, void* l) {
    __builtin_amdgcn_global_load_lds(
        (const __attribute__((address_space(1))) void*)g,
        (__attribute__((address_space(3))) void*)l, 16, 0, 0);
}

// numpy pairwise sumsq (n=64): 8 stride-8 accs of fl(x^2), tree combine.
__device__ __forceinline__ float np_sumsq64_p(const float* __restrict__ x) {
    float r[8];
    {
        float4 v0 = *(const float4*)(x);
        float4 v1 = *(const float4*)(x + 4);
        r[0] = __fmul_rn(v0.x, v0.x); r[1] = __fmul_rn(v0.y, v0.y);
        r[2] = __fmul_rn(v0.z, v0.z); r[3] = __fmul_rn(v0.w, v0.w);
        r[4] = __fmul_rn(v1.x, v1.x); r[5] = __fmul_rn(v1.y, v1.y);
        r[6] = __fmul_rn(v1.z, v1.z); r[7] = __fmul_rn(v1.w, v1.w);
    }
#pragma unroll
    for (int i = 8; i < 64; i += 8) {
        float4 v0 = *(const float4*)(x + i);
        float4 v1 = *(const float4*)(x + i + 4);
        r[0] = __fadd_rn(r[0], __fmul_rn(v0.x, v0.x));
        r[1] = __fadd_rn(r[1], __fmul_rn(v0.y, v0.y));
        r[2] = __fadd_rn(r[2], __fmul_rn(v0.z, v0.z));
        r[3] = __fadd_rn(r[3], __fmul_rn(v0.w, v0.w));
        r[4] = __fadd_rn(r[4], __fmul_rn(v1.x, v1.x));
        r[5] = __fadd_rn(r[5], __fmul_rn(v1.y, v1.y));
        r[6] = __fadd_rn(r[6], __fmul_rn(v1.z, v1.z));
        r[7] = __fadd_rn(r[7], __fmul_rn(v1.w, v1.w));
    }
    return __fadd_rn(__fadd_rn(__fadd_rn(r[0], r[1]), __fadd_rn(r[2], r[3])),
                     __fadd_rn(__fadd_rn(r[4], r[5]), __fadd_rn(r[6], r[7])));
}

// ---- precompute: code norms + f16 split-2 B-frags in MFMA lane order ----
__global__ void vq_pre(const float* __restrict__ cb, float* __restrict__ cn,
                       _Float16* __restrict__ ef) {
    const int k = blockIdx.x * 64 + threadIdx.x;
    if (k >= K) return;
    cn[k] = np_sumsq64_p(cb + (long)k * D);
    const int t = k >> 6, ct = (k >> 4) & 3, l16 = k & 15;
#pragma unroll
    for (int ch = 0; ch < 2; ++ch)
#pragma unroll
        for (int quad = 0; quad < 4; ++quad) {
            const float* p = cb + (long)k * D + ch * 32 + quad * 8;
            half8_t h1, h2;
#pragma unroll
            for (int j = 0; j < 8; ++j) {
                float x10 = __fmul_rn(p[j], 1024.0f);        // exact pow2 scale
                _Float16 g1 = (_Float16)x10;
                h1[j] = g1;
                h2[j] = (_Float16)(__fmul_rn(__fsub_rn(x10, (float)g1), 2048.0f));
            }
            const int base = t * 8192 + 128 * quad + 8 * l16;
            *(half8_t*)(ef + base + 512 * (ch * 4 + ct))       = h1;
            *(half8_t*)(ef + base + 512 * ((2 + ch) * 4 + ct)) = h2;
        }
}

// ---- main: 128 rows x ALL 1024 codes per 4-wave block; fused outputs ----
__global__ __launch_bounds__(BLOCK, 2) void vq_main(
    const float* __restrict__ z, const float* __restrict__ cb,
    const _Float16* __restrict__ ef, const float* __restrict__ cn,
    float* __restrict__ zq, float* __restrict__ idx_out) {
    // zf (128 x 68 f32 = 34816 B) unioned with two 16 KB frag buffers
    __shared__ __align__(16) char smem[34816];
    __shared__ float sS[128];
    __shared__ float sCn[K];
    __shared__ int   sBi[128];
    float*    zf   = (float*)smem;
    _Float16* bufs = (_Float16*)smem;     // buf b at bufs + b*8192

    const int tid  = threadIdx.x;
    const int lane = tid & 63;
    const int wv   = tid >> 6;
    const int quad = lane >> 4;
    const int l16  = lane & 15;
    const long rowbase = (long)blockIdx.x * 128;

    // ---- stage z (coalesced) + all code norms ----
    const float4* gz = (const float4*)(z + rowbase * D);
#pragma unroll
    for (int i = 0; i < 8; ++i) {
        int idx4 = i * BLOCK + tid;
        int r = idx4 >> 4, j = idx4 & 15;
        *(float4*)(zf + r * 68 + j * 4) = gz[idx4];
    }
#pragma unroll
    for (int i = 0; i < 4; ++i) sCn[i * 256 + tid] = cn[i * 256 + tid];
    __syncthreads();

    // row norms (exact np chain)
    if (tid < 128) sS[tid] = np_sumsq64_p(zf + tid * 68);

    // A-frags: register-resident f16 splits; wave wv -> rows wv*32 .. +31
    half8_t a1[2][2], a2[2][2];
#pragma unroll
    for (int rt = 0; rt < 2; ++rt) {
        const int row = wv * 32 + rt * 16 + l16;
#pragma unroll
        for (int ch = 0; ch < 2; ++ch) {
            const float* p = zf + row * 68 + ch * 32 + quad * 8;
            float4 f0 = *(const float4*)(p);
            float4 f1 = *(const float4*)(p + 4);
            float xs[8] = {f0.x, f0.y, f0.z, f0.w, f1.x, f1.y, f1.z, f1.w};
#pragma unroll
            for (int j = 0; j < 8; ++j) {
                _Float16 h1 = (_Float16)xs[j];
                a1[rt][ch][j] = h1;
                a2[rt][ch][j] =
                    (_Float16)(__fmul_rn(__fsub_rn(xs[j], (float)h1), 2048.0f));
            }
        }
    }
    __syncthreads();   // all zf reads done (sS + frags); sS visible

    float myS[2][4];
#pragma unroll
    for (int rt = 0; rt < 2; ++rt)
#pragma unroll
        for (int r = 0; r < 4; ++r)
            myS[rt][r] = sS[wv * 32 + rt * 16 + quad * 4 + r];

    float bv[2][4];
    int   bi[2][4];
#pragma unroll
    for (int rt = 0; rt < 2; ++rt)
#pragma unroll
        for (int r = 0; r < 4; ++r) { bv[rt][r] = INFINITY; bi[rt][r] = 0; }

    const char* eb = (const char*)ef;

    // stage tile 0 (async DMA: wave wv copies its 4 KB quarter)
    {
        const char* g = eb + wv * 4096 + lane * 16;
        char* l = (char*)bufs + wv * 4096;       // wave-uniform dest base
#pragma unroll
        for (int i = 0; i < 4; ++i) gld_lds16(g + i * 1024, l + i * 1024);
    }
    __syncthreads();   // tile 0 staged (barrier drains vmcnt)

    for (int t = 0; t < 16; ++t) {
        const _Float16* cur = bufs + (t & 1) * 8192;
        // prefetch tile t+1 into the other buffer (async, lands by barrier)
        if (t < 15) {
            const char* g = eb + (t + 1) * 16384 + wv * 4096 + lane * 16;
            char* l = (char*)bufs + ((t + 1) & 1) * 16384 + wv * 4096;
#pragma unroll
            for (int i = 0; i < 4; ++i) gld_lds16(g + i * 1024, l + i * 1024);
        }

        const _Float16* tb = cur + 8 * lane;
        const int kbase = t * 64;
#pragma unroll
        for (int ct = 0; ct < 4; ++ct) {
            half8_t b1[2], b2[2];
#pragma unroll
            for (int ch = 0; ch < 2; ++ch) {
                b1[ch] = *(const half8_t*)(tb + 512 * (ch * 4 + ct));
                b2[ch] = *(const half8_t*)(tb + 512 * ((2 + ch) * 4 + ct));
            }
            const float cnv = sCn[kbase + ct * 16 + l16];
            const int kg = kbase + ct * 16 + l16;
#pragma unroll
            for (int rt = 0; rt < 2; ++rt) {
                floatx4 aM = (floatx4){0.f, 0.f, 0.f, 0.f};
                floatx4 aC = (floatx4){0.f, 0.f, 0.f, 0.f};
                aM = __builtin_amdgcn_mfma_f32_16x16x32_f16(a1[rt][0], b1[0], aM, 0, 0, 0);
                aM = __builtin_amdgcn_mfma_f32_16x16x32_f16(a1[rt][1], b1[1], aM, 0, 0, 0);
                aC = __builtin_amdgcn_mfma_f32_16x16x32_f16(a1[rt][0], b2[0], aC, 0, 0, 0);
                aC = __builtin_amdgcn_mfma_f32_16x16x32_f16(a1[rt][1], b2[1], aC, 0, 0, 0);
                aC = __builtin_amdgcn_mfma_f32_16x16x32_f16(a2[rt][0], b1[0], aC, 0, 0, 0);
                aC = __builtin_amdgcn_mfma_f32_16x16x32_f16(a2[rt][1], b1[1], aC, 0, 0, 0);
                // C layout: col=l16 (code), row=quad*4+r
#pragma unroll
                for (int r = 0; r < 4; ++r) {
                    float ds = fmaf(aC[r], 0x1p-11f, aM[r]);   // 1024*d
                    float t2 = __fmul_rn(ds, 0x1p-9f);         // 2d, exact pow2
                    float dist = __fadd_rn(__fsub_rn(myS[rt][r], t2), cnv);
                    if (dist < bv[rt][r]) { bv[rt][r] = dist; bi[rt][r] = kg; }
                }
            }
        }
        __syncthreads();  // t+1 staged; cur reads done before t+2 overwrites
    }

    // reduce over the 16 code-columns; (val, lowest index) = first occurrence
#pragma unroll
    for (int rt = 0; rt < 2; ++rt)
#pragma unroll
        for (int r = 0; r < 4; ++r) {
            float v = bv[rt][r];
            int   x = bi[rt][r];
#pragma unroll
            for (int off = 1; off <= 8; off <<= 1) {
                float ov = __shfl_xor(v, off);
                int   ox = __shfl_xor(x, off);
                if (ov < v || (ov == v && ox < x)) { v = ov; x = ox; }
            }
            if (l16 == 0) {
                const int rl = wv * 32 + rt * 16 + quad * 4 + r;
                sBi[rl] = x;
                idx_out[rowbase + rl] = (float)x;
            }
        }
    __syncthreads();

    // ---- zq gather: zq[row] = cb[bi[row]] (cb L2-hot, coalesced writes) ----
    const float4* cb4 = (const float4*)cb;
    float4* zq4 = (float4*)(zq + rowbase * D);
#pragma unroll
    for (int i = 0; i < 8; ++i) {
        int idx4 = i * BLOCK + tid;
        int r = idx4 >> 4, j = idx4 & 15;
        zq4[idx4] = cb4[(long)sBi[r] * 16 + j];
    }
}

extern "C" void kernel_launch(void* const* d_in, const int* in_sizes, int n_in,
                              void* d_out, int out_size, void* d_ws, size_t ws_size,
                              hipStream_t stream) {
    const float* z  = (const float*)d_in[0];
    const float* cb = (const float*)d_in[1];

    const int n_rows = in_sizes[0] / D;                 // 65536
    float* zq      = (float*)d_out;
    float* idx_out = zq + (long)n_rows * D;

    float*    ws_cn = (float*)((char*)d_ws + WS_CN_OFF);
    _Float16* ws_ef = (_Float16*)((char*)d_ws + WS_EF_OFF);

    vq_pre<<<K / 64, 64, 0, stream>>>(cb, ws_cn, ws_ef);
    vq_main<<<n_rows / 128, BLOCK, 0, stream>>>(z, cb, ws_ef, ws_cn, zq, idx_out);
}